// Round 2
// baseline (1228.393 us; speedup 1.0000x reference)
//
#include <hip/hip_runtime.h>
#include <hip/hip_bf16.h>

// EyeInput: out[i, :] = eye[x[i], :] with eye = identity(16384).
// Fused one-pass: zero + one-hot scatter in a single streaming-store kernel.
// The 1 GB eye input is never read.

#define NB_FRAMES 16384
#define F4_PER_ROW (NB_FRAMES / 4)   // 4096 float4 per row
#define BLOCK 256
#define F4_PER_THREAD (F4_PER_ROW / BLOCK)  // 16

__global__ __launch_bounds__(BLOCK) void onehot_rows_kernel(
        const int* __restrict__ x, float4* __restrict__ out) {
    const int row = blockIdx.x;
    const int col = x[row];  // wave-uniform load, served from cache

    float4* rowp = out + (size_t)row * F4_PER_ROW;
    const float4 z = make_float4(0.f, 0.f, 0.f, 0.f);

    #pragma unroll
    for (int j = 0; j < F4_PER_THREAD; ++j) {
        const int f4 = j * BLOCK + threadIdx.x;   // coalesced: lane i -> f4 i
        float4 v = z;
        const int base = f4 * 4;
        if (col >= base && col < base + 4) {
            ((float*)&v)[col - base] = 1.0f;      // plant the one inline
        }
        rowp[f4] = v;
    }
}

extern "C" void kernel_launch(void* const* d_in, const int* in_sizes, int n_in,
                              void* d_out, int out_size, void* d_ws, size_t ws_size,
                              hipStream_t stream) {
    // d_in[0] = eye (float32, 16384*16384) -- unused
    // d_in[1] = x   (int32/int64 -> int32 lanes, 4096)
    const int* x = (const int*)d_in[1];
    float4* out = (float4*)d_out;
    const int n_rows = out_size / NB_FRAMES;      // 4096

    onehot_rows_kernel<<<n_rows, BLOCK, 0, stream>>>(x, out);
}